// Round 12
// baseline (654.233 us; speedup 1.0000x reference)
//
#include <hip/hip_runtime.h>
#include <cmath>

#define LSEQ   512
#define BATCH  128
#define EDIM   256
#define HDIM   128
#define GDIM   512      // 4*H2
#define NVOC   32001    // V+1 rows in emb table
#define PADROW 32000    // pad_id

typedef __attribute__((ext_vector_type(8))) _Float16 half8;
typedef __attribute__((ext_vector_type(4))) _Float16 half4;
typedef __attribute__((ext_vector_type(4))) float    f32x4;

#define LO_SCALE 4096.f
#define LO_INV   (1.f / 4096.f)

// ---------------------------------------------------------------------------
// Kernel 1: G[dir][v][n] = sum_e emb[v][e]*W_ih[n][e] + b[n], f32 out.
// hi/lo f16 split (3 MFMAs) => f32-equivalent accuracy. (passed rounds 5-9)
// ---------------------------------------------------------------------------
__global__ __launch_bounds__(512) void g_gemm(
    const float* __restrict__ emb,
    const float* __restrict__ Wf, const float* __restrict__ Wb,
    const float* __restrict__ bf, const float* __restrict__ bb,
    float* __restrict__ G)
{
    const int nb  = blockIdx.x & 7;
    const int dir = blockIdx.x >> 3;
    const int mb  = blockIdx.y;   // 0..250
    const float* W    = dir ? Wb : Wf;
    const float* bias = dir ? bb : bf;
    float* Gd = G + (size_t)dir * NVOC * GDIM;

    __shared__ _Float16 Ah[128][136], Al[128][136];
    __shared__ _Float16 Bh[64][136],  Bl[64][136];

    const int tid  = threadIdx.x;
    const int m0   = mb * 128;
    const int n0   = nb * 64;
    const int w    = tid >> 6;
    const int lane = tid & 63;
    const int lr   = lane & 15;
    const int lg   = lane >> 4;

    f32x4 acc_m[4], acc_x[4];
    #pragma unroll
    for (int nt = 0; nt < 4; ++nt) {
        acc_m[nt] = (f32x4){0.f, 0.f, 0.f, 0.f};
        acc_x[nt] = (f32x4){0.f, 0.f, 0.f, 0.f};
    }

    for (int kh = 0; kh < 2; ++kh) {
        __syncthreads();
        #pragma unroll
        for (int it = 0; it < 8; ++it) {          // A: 128 x 128
            int ch  = tid + 512 * it;
            int row = ch >> 5;
            int c4  = ch & 31;
            int v   = m0 + row; if (v > PADROW) v = PADROW;
            f32x4 s = *(const f32x4*)(emb + (size_t)v * EDIM + kh * 128 + c4 * 4);
            half4 hv, lv;
            #pragma unroll
            for (int jj = 0; jj < 4; ++jj) {
                _Float16 hi = (_Float16)s[jj];
                hv[jj] = hi;
                lv[jj] = (_Float16)((s[jj] - (float)hi) * LO_SCALE);
            }
            *(half4*)&Ah[row][c4 * 4] = hv;
            *(half4*)&Al[row][c4 * 4] = lv;
        }
        #pragma unroll
        for (int it = 0; it < 4; ++it) {          // B: 64 x 128
            int ch  = tid + 512 * it;
            int row = ch >> 5;
            int c4  = ch & 31;
            f32x4 s = *(const f32x4*)(W + (size_t)(n0 + row) * EDIM + kh * 128 + c4 * 4);
            half4 hv, lv;
            #pragma unroll
            for (int jj = 0; jj < 4; ++jj) {
                _Float16 hi = (_Float16)s[jj];
                hv[jj] = hi;
                lv[jj] = (_Float16)((s[jj] - (float)hi) * LO_SCALE);
            }
            *(half4*)&Bh[row][c4 * 4] = hv;
            *(half4*)&Bl[row][c4 * 4] = lv;
        }
        __syncthreads();

        #pragma unroll
        for (int ks = 0; ks < 4; ++ks) {
            half8 ah = *(const half8*)&Ah[16 * w + lr][32 * ks + 8 * lg];
            half8 al = *(const half8*)&Al[16 * w + lr][32 * ks + 8 * lg];
            #pragma unroll
            for (int nt = 0; nt < 4; ++nt) {
                half8 bh = *(const half8*)&Bh[16 * nt + lr][32 * ks + 8 * lg];
                half8 bl = *(const half8*)&Bl[16 * nt + lr][32 * ks + 8 * lg];
                acc_m[nt] = __builtin_amdgcn_mfma_f32_16x16x32_f16(ah, bh, acc_m[nt], 0, 0, 0);
                acc_x[nt] = __builtin_amdgcn_mfma_f32_16x16x32_f16(al, bh, acc_x[nt], 0, 0, 0);
                acc_x[nt] = __builtin_amdgcn_mfma_f32_16x16x32_f16(ah, bl, acc_x[nt], 0, 0, 0);
            }
        }
    }

    // C/D: col = lane&15 (n), row = (lane>>4)*4 + reg (m)
    #pragma unroll
    for (int nt = 0; nt < 4; ++nt) {
        int ng = n0 + nt * 16 + lr;
        float bv = bias[ng];
        #pragma unroll
        for (int r = 0; r < 4; ++r) {
            int v = m0 + 16 * w + 4 * lg + r;
            if (v < NVOC)
                Gd[(size_t)v * GDIM + ng] = acc_m[nt][r] + acc_x[nt][r] * LO_INV + bv;
        }
    }
}

// ---------------------------------------------------------------------------
// Kernel 2: LSTM scan v8 = v7 with the MFMA issued via the BUILTIN instead of
// inline asm. v7's corruption mechanism: LLVM's hazard recognizer identifies
// MFMA by opcode, so an inline-asm MFMA gets NO mandatory wait-states before
// the VALU reads of its destination (builtin path inserts them). Round 5
// proved builtin + hi/lo + this fragment layout numerically correct.
// W_hh stays PINNED IN AGPRS ("+a"): builtin MFMA operands are AV-class on
// gfx950 (A/B from VGPR or AGPR) -> consumed in place, zero per-step W traffic
// (r8/r9 showed the allocator otherwise re-fetches W every step).
// ---------------------------------------------------------------------------
__device__ __forceinline__ float sigm(float x) {
    return __builtin_amdgcn_rcpf(1.f + __builtin_amdgcn_exp2f(-1.4426950408889634f * x));
}
__device__ __forceinline__ float tanh_fast(float x) {
    return 1.f - 2.f * __builtin_amdgcn_rcpf(1.f + __builtin_amdgcn_exp2f(2.8853900817779268f * x));
}

__global__ __launch_bounds__(512, 2) void lstm_scan_v8(
    const int*   __restrict__ tokens,
    const float* __restrict__ Whh_f, const float* __restrict__ Whh_b,
    const float* __restrict__ G,
    float* __restrict__ out)
{
    const int dir = blockIdx.x >> 7;
    const int b   = blockIdx.x & 127;
    const float* Whh = dir ? Whh_b : Whh_f;
    const float* Gd  = G + (size_t)dir * NVOC * GDIM;

    __shared__ int      tok[LSEQ];
    __shared__ _Float16 hh[2][HDIM];   // h hi (f16)
    __shared__ _Float16 hl[2][HDIM];   // h lo (x4096, f16)

    const int tid  = threadIdx.x;
    const int w    = tid >> 6;
    const int lane = tid & 63;
    const int lr   = lane & 15;
    const int lg   = lane >> 4;
    const int j    = 16 * w + lr;      // h/output column this lane owns

    tok[tid] = tokens[(size_t)tid * BATCH + b];
    if (tid < HDIM) {
        hh[0][tid] = (_Float16)0.f; hh[1][tid] = (_Float16)0.f;
        hl[0][tid] = (_Float16)0.f; hl[1][tid] = (_Float16)0.f;
    }

    // W_hh B-fragments (hi/lo f16): tile tt, k-step ks:
    // lane supplies W[n][k], n = 128*tt + j, k = 32*ks + 8*lg + jj
    // (fragment layout identical to the PASSING g_gemm B-side).
    half8 wh[4][4], wl[4][4];
    #pragma unroll
    for (int tt = 0; tt < 4; ++tt) {
        const float* wrow = Whh + (size_t)(128 * tt + j) * HDIM;
        #pragma unroll
        for (int ks = 0; ks < 4; ++ks) {
            const float* wp = wrow + 32 * ks + 8 * lg;
            half8 hv, lv;
            #pragma unroll
            for (int jj = 0; jj < 8; ++jj) {
                float x = wp[jj];
                _Float16 hi = (_Float16)x;
                hv[jj] = hi;
                lv[jj] = (_Float16)((x - (float)hi) * LO_SCALE);
            }
            wh[tt][ks] = hv;
            wl[tt][ks] = lv;
        }
    }
    // Pin all 32 fragments into AGPRs (128 AGPRs; arch-VGPR budget untouched;
    // values become opaque => no rematerialization, no per-step refetch).
    #pragma unroll
    for (int tt = 0; tt < 4; ++tt)
        #pragma unroll
        for (int ks = 0; ks < 4; ++ks) {
            asm volatile("" : "+a"(wh[tt][ks]));
            asm volatile("" : "+a"(wl[tt][ks]));
        }
    __syncthreads();

    auto rowof = [&](int t) -> int {
        int l  = dir ? (LSEQ - 1 - t) : t;
        int tk = tok[l];
        return (tk < 0) ? PADROW : tk;
    };

    float xgA[4], xgB[4];
    {
        size_t ro = (size_t)rowof(0) * GDIM;
        #pragma unroll
        for (int gt = 0; gt < 4; ++gt) xgA[gt] = Gd[ro + 128 * gt + j];
    }

    float c = 0.f;
    const size_t out_base = (size_t)b * 256 + (size_t)dir * HDIM + j;

    auto step = [&](int t, float (&xgc)[4], float (&xgn)[4]) {
        const int l = dir ? (LSEQ - 1 - t) : t;

        // prefetch next step's xg (stays in flight across the barrier)
        if (t + 1 < LSEQ) {
            size_t ro = (size_t)rowof(t + 1) * GDIM;
            #pragma unroll
            for (int gt = 0; gt < 4; ++gt) xgn[gt] = Gd[ro + 128 * gt + j];
        }

        // A-fragments: every lane of an lr-group reads the same 16B of h
        // -> all 16 m-rows = h (broadcast), conflict-free LDS reads.
        const _Float16* hbH = hh[t & 1];
        const _Float16* hbL = hl[t & 1];
        half8 ah[4], al[4];
        #pragma unroll
        for (int ks = 0; ks < 4; ++ks) {
            ah[ks] = *(const half8*)&hbH[32 * ks + 8 * lg];
            al[ks] = *(const half8*)&hbL[32 * ks + 8 * lg];
        }

        f32x4 am[4], ax[4];
        #pragma unroll
        for (int tt = 0; tt < 4; ++tt) {
            am[tt] = (f32x4){0.f, 0.f, 0.f, 0.f};
            ax[tt] = (f32x4){0.f, 0.f, 0.f, 0.f};
        }
        // 48 MFMAs on the matrix pipe (builtin: hazards + scheduling handled).
        #pragma unroll
        for (int ks = 0; ks < 4; ++ks) {
            #pragma unroll
            for (int tt = 0; tt < 4; ++tt)
                am[tt] = __builtin_amdgcn_mfma_f32_16x16x32_f16(ah[ks], wh[tt][ks], am[tt], 0, 0, 0);
            #pragma unroll
            for (int tt = 0; tt < 4; ++tt)
                ax[tt] = __builtin_amdgcn_mfma_f32_16x16x32_f16(al[ks], wh[tt][ks], ax[tt], 0, 0, 0);
            #pragma unroll
            for (int tt = 0; tt < 4; ++tt)
                ax[tt] = __builtin_amdgcn_mfma_f32_16x16x32_f16(ah[ks], wl[tt][ks], ax[tt], 0, 0, 0);
        }

        // rows are broadcast-identical: reg 0 holds gate n = 128*tt + j
        float g0 = am[0][0] + ax[0][0] * LO_INV + xgc[0];
        float g1 = am[1][0] + ax[1][0] * LO_INV + xgc[1];
        float g2 = am[2][0] + ax[2][0] * LO_INV + xgc[2];
        float g3 = am[3][0] + ax[3][0] * LO_INV + xgc[3];

        float iv = sigm(g0);
        float fv = sigm(g1);
        float gv = tanh_fast(g2);
        float ov = sigm(g3);
        c = fv * c + iv * gv;
        float h = ov * tanh_fast(c);
        if (tok[l] < 0) { c = 0.f; h = 0.f; }   // wave-uniform branch

        if (lg == 0) {                           // one writer per column
            out[(size_t)l * (BATCH * 256) + out_base] = h;
            _Float16 hhi = (_Float16)h;
            hh[(t + 1) & 1][j] = hhi;
            hl[(t + 1) & 1][j] = (_Float16)((h - (float)hhi) * LO_SCALE);
        }
        // LDS visibility only; keep global prefetch (vmcnt) in flight
        asm volatile("s_waitcnt lgkmcnt(0)" ::: "memory");
        __builtin_amdgcn_s_barrier();
    };

    for (int t = 0; t < LSEQ; t += 2) {
        step(t,     xgA, xgB);
        step(t + 1, xgB, xgA);
    }
}

// ---------------------------------------------------------------------------
extern "C" void kernel_launch(void* const* d_in, const int* in_sizes, int n_in,
                              void* d_out, int out_size, void* d_ws, size_t ws_size,
                              hipStream_t stream) {
    const int*   tokens = (const int*)  d_in[0];
    // d_in[1] = mask (unused; token==-1 <=> mask==0)
    const float* emb    = (const float*)d_in[2];
    const float* W_ih_f = (const float*)d_in[3];
    const float* W_hh_f = (const float*)d_in[4];
    const float* b_f    = (const float*)d_in[5];
    const float* W_ih_b = (const float*)d_in[6];
    const float* W_hh_b = (const float*)d_in[7];
    const float* b_b    = (const float*)d_in[8];

    float* G = (float*)d_ws;   // [2][NVOC][512] f32 = 131 MB

    g_gemm<<<dim3(16, 251), 512, 0, stream>>>(emb, W_ih_f, W_ih_b, b_f, b_b, G);
    lstm_scan_v8<<<256, 512, 0, stream>>>(tokens, W_hh_f, W_hh_b, G,
                                          (float*)d_out);
}